// Round 2
// baseline (267.487 us; speedup 1.0000x reference)
//
#include <hip/hip_runtime.h>
#include <math.h>

#define EPSF 1e-8f

constexpr int B = 262144;
constexpr int T = 128;
constexpr int E = 5;
constexpr int K = 20;

// ws[0] = sum((pred-targ)^2 * mask), ws[1] = sum(mask), ws[2] = sum(ll)
__global__ void k_init(float* ws) {
    if (threadIdx.x < 4) ws[threadIdx.x] = 0.0f;
}

// Each block covers 1024 consecutive float4s (4 coalesced chunks of 256).
// All 12 loads are issued before any consumption -> 12 KB in flight per wave.
__global__ __launch_bounds__(256) void k_state(const float4* __restrict__ pred,
                                               const float4* __restrict__ targ,
                                               const float4* __restrict__ mask,
                                               float* __restrict__ ws) {
    const int base = blockIdx.x * 1024 + threadIdx.x;

    float4 p0 = pred[base];
    float4 p1 = pred[base + 256];
    float4 p2 = pred[base + 512];
    float4 p3 = pred[base + 768];
    float4 t0 = targ[base];
    float4 t1 = targ[base + 256];
    float4 t2 = targ[base + 512];
    float4 t3 = targ[base + 768];
    float4 w0 = mask[base];
    float4 w1 = mask[base + 256];
    float4 w2 = mask[base + 512];
    float4 w3 = mask[base + 768];

    float s = 0.f, m = 0.f;
    {
        float d;
        d = p0.x - t0.x; s += d * d * w0.x; m += w0.x;
        d = p0.y - t0.y; s += d * d * w0.y; m += w0.y;
        d = p0.z - t0.z; s += d * d * w0.z; m += w0.z;
        d = p0.w - t0.w; s += d * d * w0.w; m += w0.w;
        d = p1.x - t1.x; s += d * d * w1.x; m += w1.x;
        d = p1.y - t1.y; s += d * d * w1.y; m += w1.y;
        d = p1.z - t1.z; s += d * d * w1.z; m += w1.z;
        d = p1.w - t1.w; s += d * d * w1.w; m += w1.w;
        d = p2.x - t2.x; s += d * d * w2.x; m += w2.x;
        d = p2.y - t2.y; s += d * d * w2.y; m += w2.y;
        d = p2.z - t2.z; s += d * d * w2.z; m += w2.z;
        d = p2.w - t2.w; s += d * d * w2.w; m += w2.w;
        d = p3.x - t3.x; s += d * d * w3.x; m += w3.x;
        d = p3.y - t3.y; s += d * d * w3.y; m += w3.y;
        d = p3.z - t3.z; s += d * d * w3.z; m += w3.z;
        d = p3.w - t3.w; s += d * d * w3.w; m += w3.w;
    }

    #pragma unroll
    for (int off = 32; off > 0; off >>= 1) {
        s += __shfl_down(s, off);
        m += __shfl_down(m, off);
    }
    __shared__ float ss[4], sm[4];
    int wid = threadIdx.x >> 6;
    if ((threadIdx.x & 63) == 0) { ss[wid] = s; sm[wid] = m; }
    __syncthreads();
    if (threadIdx.x == 0) {
        atomicAdd(&ws[0], ss[0] + ss[1] + ss[2] + ss[3]);
        atomicAdd(&ws[1], sm[0] + sm[1] + sm[2] + sm[3]);
    }
}

__global__ __launch_bounds__(256) void k_surv(const float* __restrict__ hz,
                                              const float* __restrict__ et,
                                              const float* __restrict__ ei,
                                              float* __restrict__ ws) {
    int b = blockIdx.x * 256 + threadIdx.x;
    float ll = 0.f;
    #pragma unroll
    for (int e = 0; e < E; ++e) {
        float t = et[b * E + e];
        float ind = ei[b * E + e];
        // searchsorted(bounds={0.5,...,10.0}, t, 'left') == #bounds < t.
        // bounds are exact multiples of 0.5: m*0.5 < t  <=>  m < 2t (exact).
        float u = 2.0f * t;
        int idx = (int)floorf(u);
        if ((float)idx == u) idx -= 1;
        idx = min(max(idx, 0), K - 1);
        const float4* row = (const float4*)(hz + ((size_t)e * B + b) * K);
        float cum = 0.f, ls = 0.f, lp = 0.f;
        #pragma unroll
        for (int q = 0; q < K / 4; ++q) {
            float4 v = row[q];
            float xs[4] = {v.x, v.y, v.z, v.w};
            #pragma unroll
            for (int j = 0; j < 4; ++j) {
                int k = q * 4 + j;
                float p = 1.0f / (1.0f + __expf(-xs[j]));
                if (k == idx) { ls = cum; lp = __logf(p + EPSF); }
                cum += __logf(1.0f - p + EPSF);   // after the check: exclusive prefix
            }
        }
        ll += ls + (ind > 0.5f ? lp : 0.0f);
    }
    #pragma unroll
    for (int off = 32; off > 0; off >>= 1) ll += __shfl_down(ll, off);
    __shared__ float sl[4];
    int wid = threadIdx.x >> 6;
    if ((threadIdx.x & 63) == 0) sl[wid] = ll;
    __syncthreads();
    if (threadIdx.x == 0) atomicAdd(&ws[2], sl[0] + sl[1] + sl[2] + sl[3]);
}

__global__ void k_fin(const float* __restrict__ ws, float* __restrict__ out) {
    if (threadIdx.x == 0 && blockIdx.x == 0) {
        float state_loss = ws[0] / (ws[1] + EPSF);
        float surv_loss = -ws[2] / (float)(E * B);
        out[0] = state_loss + surv_loss;
    }
}

extern "C" void kernel_launch(void* const* d_in, const int* in_sizes, int n_in,
                              void* d_out, int out_size, void* d_ws, size_t ws_size,
                              hipStream_t stream) {
    const float* pred = (const float*)d_in[0];
    const float* hz   = (const float*)d_in[1];
    const float* targ = (const float*)d_in[2];
    const float* mask = (const float*)d_in[3];
    const float* et   = (const float*)d_in[4];
    const float* ei   = (const float*)d_in[5];
    float* out = (float*)d_out;
    float* ws  = (float*)d_ws;

    hipLaunchKernelGGL(k_init, dim3(1), dim3(64), 0, stream, ws);

    // n4 = B*T/4 = 8,388,608 float4s; 8192 blocks * 256 threads * 4 float4 = exact fit
    hipLaunchKernelGGL(k_state, dim3(8192), dim3(256), 0, stream,
                       (const float4*)pred, (const float4*)targ,
                       (const float4*)mask, ws);

    hipLaunchKernelGGL(k_surv, dim3(B / 256), dim3(256), 0, stream, hz, et, ei, ws);

    hipLaunchKernelGGL(k_fin, dim3(1), dim3(1), 0, stream, ws, out);
}

// Round 4
// 111.742 us; speedup vs baseline: 2.3938x; 2.3938x over previous
//
#include <hip/hip_runtime.h>
#include <math.h>

#define EPSF 1e-8f

constexpr int B = 262144;
constexpr int T = 128;
constexpr int E = 5;
constexpr int K = 20;
constexpr int SB = 1024;   // state partial-sum blocks
constexpr int VB = 1024;   // survival partial-sum blocks

// ws layout (floats): [0,SB) s-partials | [SB,2SB) mask-partials | [2SB,2SB+VB) ll-partials
// Every slot is unconditionally overwritten each call -> no init kernel needed.

// Each block covers 8192 consecutive float4s (32/thread, 8 batches of 4 per stream).
// A/B ping-pong: batch j+1's 12 loads are issued before batch j is consumed.
__global__ __launch_bounds__(256, 4) void k_state(const float4* __restrict__ pred,
                                                  const float4* __restrict__ targ,
                                                  const float4* __restrict__ mask,
                                                  float* __restrict__ ws) {
    const int tb = blockIdx.x * 8192 + threadIdx.x;
    float s = 0.f, m = 0.f;

    float4 pa0, pa1, pa2, pa3, ta0, ta1, ta2, ta3, wa0, wa1, wa2, wa3;
    float4 pb0, pb1, pb2, pb3, tb0, tb1, tb2, tb3, wb0, wb1, wb2, wb3;

#define LOADA(c) \
    pa0 = pred[tb + (c + 0) * 256]; pa1 = pred[tb + (c + 1) * 256]; \
    pa2 = pred[tb + (c + 2) * 256]; pa3 = pred[tb + (c + 3) * 256]; \
    ta0 = targ[tb + (c + 0) * 256]; ta1 = targ[tb + (c + 1) * 256]; \
    ta2 = targ[tb + (c + 2) * 256]; ta3 = targ[tb + (c + 3) * 256]; \
    wa0 = mask[tb + (c + 0) * 256]; wa1 = mask[tb + (c + 1) * 256]; \
    wa2 = mask[tb + (c + 2) * 256]; wa3 = mask[tb + (c + 3) * 256];

#define LOADB(c) \
    pb0 = pred[tb + (c + 0) * 256]; pb1 = pred[tb + (c + 1) * 256]; \
    pb2 = pred[tb + (c + 2) * 256]; pb3 = pred[tb + (c + 3) * 256]; \
    tb0 = targ[tb + (c + 0) * 256]; tb1 = targ[tb + (c + 1) * 256]; \
    tb2 = targ[tb + (c + 2) * 256]; tb3 = targ[tb + (c + 3) * 256]; \
    wb0 = mask[tb + (c + 0) * 256]; wb1 = mask[tb + (c + 1) * 256]; \
    wb2 = mask[tb + (c + 2) * 256]; wb3 = mask[tb + (c + 3) * 256];

// NOTE: macro params must not be named x/y/z/w (member-access tokens get substituted)
#define C1(P_, T_, W_) { float d; \
    d = P_.x - T_.x; s += d * d * W_.x; m += W_.x; \
    d = P_.y - T_.y; s += d * d * W_.y; m += W_.y; \
    d = P_.z - T_.z; s += d * d * W_.z; m += W_.z; \
    d = P_.w - T_.w; s += d * d * W_.w; m += W_.w; }

#define CONSA C1(pa0, ta0, wa0) C1(pa1, ta1, wa1) C1(pa2, ta2, wa2) C1(pa3, ta3, wa3)
#define CONSB C1(pb0, tb0, wb0) C1(pb1, tb1, wb1) C1(pb2, tb2, wb2) C1(pb3, tb3, wb3)

    LOADA(0)
    LOADB(4)
    CONSA
    LOADA(8)
    CONSB
    LOADB(12)
    CONSA
    LOADA(16)
    CONSB
    LOADB(20)
    CONSA
    LOADA(24)
    CONSB
    LOADB(28)
    CONSA
    CONSB

#undef LOADA
#undef LOADB
#undef C1
#undef CONSA
#undef CONSB

    #pragma unroll
    for (int off = 32; off > 0; off >>= 1) {
        s += __shfl_down(s, off);
        m += __shfl_down(m, off);
    }
    __shared__ float ss[4], sm[4];
    int wid = threadIdx.x >> 6;
    if ((threadIdx.x & 63) == 0) { ss[wid] = s; sm[wid] = m; }
    __syncthreads();
    if (threadIdx.x == 0) {
        ws[blockIdx.x]      = ss[0] + ss[1] + ss[2] + ss[3];
        ws[SB + blockIdx.x] = sm[0] + sm[1] + sm[2] + sm[3];
    }
}

__global__ __launch_bounds__(256) void k_surv(const float* __restrict__ hz,
                                              const float* __restrict__ et,
                                              const float* __restrict__ ei,
                                              float* __restrict__ ws) {
    int b = blockIdx.x * 256 + threadIdx.x;
    float ll = 0.f;
    #pragma unroll
    for (int e = 0; e < E; ++e) {
        float t = et[b * E + e];
        float ind = ei[b * E + e];
        // searchsorted(bounds={0.5,...,10.0}, t, 'left') == #bounds < t.
        // bounds are exact multiples of 0.5: m*0.5 < t  <=>  m < 2t (exact).
        float u = 2.0f * t;
        int idx = (int)floorf(u);
        if ((float)idx == u) idx -= 1;
        idx = min(max(idx, 0), K - 1);
        const float4* row = (const float4*)(hz + ((size_t)e * B + b) * K);
        float cum = 0.f, ls = 0.f, lp = 0.f;
        #pragma unroll
        for (int q = 0; q < K / 4; ++q) {
            float4 v = row[q];
            float xs[4] = {v.x, v.y, v.z, v.w};
            #pragma unroll
            for (int j = 0; j < 4; ++j) {
                int k = q * 4 + j;
                float p = 1.0f / (1.0f + __expf(-xs[j]));
                if (k == idx) { ls = cum; lp = __logf(p + EPSF); }
                cum += __logf(1.0f - p + EPSF);   // after the check: exclusive prefix
            }
        }
        ll += ls + (ind > 0.5f ? lp : 0.0f);
    }
    #pragma unroll
    for (int off = 32; off > 0; off >>= 1) ll += __shfl_down(ll, off);
    __shared__ float sl[4];
    int wid = threadIdx.x >> 6;
    if ((threadIdx.x & 63) == 0) sl[wid] = ll;
    __syncthreads();
    if (threadIdx.x == 0)
        ws[2 * SB + blockIdx.x] = sl[0] + sl[1] + sl[2] + sl[3];
}

__global__ __launch_bounds__(256) void k_fin(const float* __restrict__ ws,
                                             float* __restrict__ out) {
    int tid = threadIdx.x;
    float s = 0.f, m = 0.f, l = 0.f;
    #pragma unroll
    for (int i = 0; i < SB / 256; ++i) {
        s += ws[tid + i * 256];
        m += ws[SB + tid + i * 256];
    }
    #pragma unroll
    for (int i = 0; i < VB / 256; ++i)
        l += ws[2 * SB + tid + i * 256];
    #pragma unroll
    for (int off = 32; off > 0; off >>= 1) {
        s += __shfl_down(s, off);
        m += __shfl_down(m, off);
        l += __shfl_down(l, off);
    }
    __shared__ float as[4], am[4], al[4];
    int wid = tid >> 6;
    if ((tid & 63) == 0) { as[wid] = s; am[wid] = m; al[wid] = l; }
    __syncthreads();
    if (tid == 0) {
        float S = as[0] + as[1] + as[2] + as[3];
        float M = am[0] + am[1] + am[2] + am[3];
        float L = al[0] + al[1] + al[2] + al[3];
        out[0] = S / (M + EPSF) - L / (float)(E * B);
    }
}

extern "C" void kernel_launch(void* const* d_in, const int* in_sizes, int n_in,
                              void* d_out, int out_size, void* d_ws, size_t ws_size,
                              hipStream_t stream) {
    const float* pred = (const float*)d_in[0];
    const float* hz   = (const float*)d_in[1];
    const float* targ = (const float*)d_in[2];
    const float* mask = (const float*)d_in[3];
    const float* et   = (const float*)d_in[4];
    const float* ei   = (const float*)d_in[5];
    float* out = (float*)d_out;
    float* ws  = (float*)d_ws;

    // n4 = B*T/4 = 8,388,608 float4s; 1024 blocks * 256 threads * 32 float4 = exact fit
    hipLaunchKernelGGL(k_state, dim3(SB), dim3(256), 0, stream,
                       (const float4*)pred, (const float4*)targ,
                       (const float4*)mask, ws);

    hipLaunchKernelGGL(k_surv, dim3(VB), dim3(256), 0, stream, hz, et, ei, ws);

    hipLaunchKernelGGL(k_fin, dim3(1), dim3(256), 0, stream, ws, out);
}

// Round 5
// 96.161 us; speedup vs baseline: 2.7817x; 1.1620x over previous
//
#include <hip/hip_runtime.h>
#include <math.h>

#define EPSF 1e-8f

constexpr int B = 262144;
constexpr int T = 128;
constexpr int E = 5;
constexpr int K = 20;
constexpr int SGRID = 2048;   // state blocks (2048*256*16 float4 = B*T/4 exact)
constexpr int VGRID = 1024;   // survival blocks (1024*256 = B exact)

// ws layout (floats): [0,SGRID) s-partials | [SGRID,2*SGRID) mask-partials
//                     | [2*SGRID, 2*SGRID+VGRID) ll-partials
// Every slot is unconditionally overwritten each call -> no init needed.

__global__ __launch_bounds__(256) void k_main(const float4* __restrict__ pred,
                                              const float4* __restrict__ targ,
                                              const float4* __restrict__ mask,
                                              const float* __restrict__ hz,
                                              const float* __restrict__ et,
                                              const float* __restrict__ ei,
                                              float* __restrict__ ws) {
    const int tid = threadIdx.x;

    if (blockIdx.x < VGRID) {
        // ---------------- survival role (launches first, overlaps state stream) ---------
        int b = blockIdx.x * 256 + tid;
        float ll = 0.f;
        #pragma unroll
        for (int e = 0; e < E; ++e) {
            float t = et[b * E + e];
            float ind = ei[b * E + e];
            // searchsorted(bounds={0.5,...,10.0}, t, 'left') == #bounds < t.
            // bounds are exact multiples of 0.5: j*0.5 < t  <=>  j < 2t (exact).
            float u = 2.0f * t;
            int idx = (int)floorf(u);
            if ((float)idx == u) idx -= 1;
            idx = min(max(idx, 0), K - 1);
            const float4* row = (const float4*)(hz + ((size_t)e * B + b) * K);
            float cum = 0.f, ls = 0.f, lp = 0.f;
            #pragma unroll
            for (int q = 0; q < K / 4; ++q) {
                float4 v = row[q];
                float xs[4] = {v.x, v.y, v.z, v.w};
                #pragma unroll
                for (int j = 0; j < 4; ++j) {
                    int k = q * 4 + j;
                    float p = 1.0f / (1.0f + __expf(-xs[j]));
                    if (k == idx) { ls = cum; lp = __logf(p + EPSF); }
                    cum += __logf(1.0f - p + EPSF);   // after the check: exclusive prefix
                }
            }
            ll += ls + (ind > 0.5f ? lp : 0.0f);
        }
        #pragma unroll
        for (int off = 32; off > 0; off >>= 1) ll += __shfl_down(ll, off);
        __shared__ float sl[4];
        int wid = tid >> 6;
        if ((tid & 63) == 0) sl[wid] = ll;
        __syncthreads();
        if (tid == 0)
            ws[2 * SGRID + blockIdx.x] = sl[0] + sl[1] + sl[2] + sl[3];
        return;
    }

    // ---------------- state role: 16 float4 positions/thread, A/B ping-pong -------------
    const int sblk = blockIdx.x - VGRID;
    const int tb4 = sblk * 4096 + tid;
    float s = 0.f, m = 0.f;

    float4 pa0, pa1, ta0, ta1, wa0, wa1;
    float4 pb0, pb1, tb0, tb1, wb0, wb1;

#define LOADA(c) \
    pa0 = pred[tb4 + (c + 0) * 256]; pa1 = pred[tb4 + (c + 1) * 256]; \
    ta0 = targ[tb4 + (c + 0) * 256]; ta1 = targ[tb4 + (c + 1) * 256]; \
    wa0 = mask[tb4 + (c + 0) * 256]; wa1 = mask[tb4 + (c + 1) * 256];

#define LOADB(c) \
    pb0 = pred[tb4 + (c + 0) * 256]; pb1 = pred[tb4 + (c + 1) * 256]; \
    tb0 = targ[tb4 + (c + 0) * 256]; tb1 = targ[tb4 + (c + 1) * 256]; \
    wb0 = mask[tb4 + (c + 0) * 256]; wb1 = mask[tb4 + (c + 1) * 256];

// NOTE: macro params must not be named x/y/z/w (member-access tokens get substituted)
#define C1(P_, T_, W_) { float d_; \
    d_ = P_.x - T_.x; s += d_ * d_ * W_.x; m += W_.x; \
    d_ = P_.y - T_.y; s += d_ * d_ * W_.y; m += W_.y; \
    d_ = P_.z - T_.z; s += d_ * d_ * W_.z; m += W_.z; \
    d_ = P_.w - T_.w; s += d_ * d_ * W_.w; m += W_.w; }

#define CONSA C1(pa0, ta0, wa0) C1(pa1, ta1, wa1)
#define CONSB C1(pb0, tb0, wb0) C1(pb1, tb1, wb1)

    LOADA(0)
    LOADB(2)
    CONSA
    LOADA(4)
    CONSB
    LOADB(6)
    CONSA
    LOADA(8)
    CONSB
    LOADB(10)
    CONSA
    LOADA(12)
    CONSB
    LOADB(14)
    CONSA
    CONSB

#undef LOADA
#undef LOADB
#undef C1
#undef CONSA
#undef CONSB

    #pragma unroll
    for (int off = 32; off > 0; off >>= 1) {
        s += __shfl_down(s, off);
        m += __shfl_down(m, off);
    }
    __shared__ float ss[4], sm[4];
    int wid = tid >> 6;
    if ((tid & 63) == 0) { ss[wid] = s; sm[wid] = m; }
    __syncthreads();
    if (tid == 0) {
        ws[sblk]         = ss[0] + ss[1] + ss[2] + ss[3];
        ws[SGRID + sblk] = sm[0] + sm[1] + sm[2] + sm[3];
    }
}

__global__ __launch_bounds__(256) void k_fin(const float* __restrict__ ws,
                                             float* __restrict__ out) {
    int tid = threadIdx.x;
    float s = 0.f, m = 0.f, l = 0.f;
    #pragma unroll
    for (int i = 0; i < SGRID / 256; ++i) {
        s += ws[tid + i * 256];
        m += ws[SGRID + tid + i * 256];
    }
    #pragma unroll
    for (int i = 0; i < VGRID / 256; ++i)
        l += ws[2 * SGRID + tid + i * 256];
    #pragma unroll
    for (int off = 32; off > 0; off >>= 1) {
        s += __shfl_down(s, off);
        m += __shfl_down(m, off);
        l += __shfl_down(l, off);
    }
    __shared__ float as[4], am[4], al[4];
    int wid = tid >> 6;
    if ((tid & 63) == 0) { as[wid] = s; am[wid] = m; al[wid] = l; }
    __syncthreads();
    if (tid == 0) {
        float S = as[0] + as[1] + as[2] + as[3];
        float M = am[0] + am[1] + am[2] + am[3];
        float L = al[0] + al[1] + al[2] + al[3];
        out[0] = S / (M + EPSF) - L / (float)(E * B);
    }
}

extern "C" void kernel_launch(void* const* d_in, const int* in_sizes, int n_in,
                              void* d_out, int out_size, void* d_ws, size_t ws_size,
                              hipStream_t stream) {
    const float* pred = (const float*)d_in[0];
    const float* hz   = (const float*)d_in[1];
    const float* targ = (const float*)d_in[2];
    const float* mask = (const float*)d_in[3];
    const float* et   = (const float*)d_in[4];
    const float* ei   = (const float*)d_in[5];
    float* out = (float*)d_out;
    float* ws  = (float*)d_ws;

    hipLaunchKernelGGL(k_main, dim3(VGRID + SGRID), dim3(256), 0, stream,
                       (const float4*)pred, (const float4*)targ,
                       (const float4*)mask, hz, et, ei, ws);

    hipLaunchKernelGGL(k_fin, dim3(1), dim3(256), 0, stream, ws, out);
}